// Round 1
// baseline (154.469 us; speedup 1.0000x reference)
//
#include <hip/hip_runtime.h>
#include <hip/hip_bf16.h>

#define IMG 256
#define TS 20

typedef unsigned short u16;
typedef __bf16 bf16x8 __attribute__((ext_vector_type(8)));
typedef float f32x4 __attribute__((ext_vector_type(4)));

__device__ __forceinline__ double cc1d(double x) {
    const double A = -0.75;
    return ((A + 2.0) * x - (A + 3.0)) * x * x + 1.0;
}
__device__ __forceinline__ double cc2d(double x) {
    const double A = -0.75;
    return ((A * x - 5.0 * A) * x + 8.0 * A) * x - 4.0 * A;
}

// fp32 -> bf16 round-to-nearest-even, bit form
__device__ __forceinline__ u16 f2bf(float f) {
    unsigned u = __float_as_uint(f);
    u = u + 0x7fffu + ((u >> 16) & 1u);
    return (u16)(u >> 16);
}

// ---------------------------------------------------------------------------
// Kernel 1: build P_t = M_{t-1} ... M_0 (bf16, row-major), one block per (o,t).
// Row o of P_t = e_o^T M_{t-1} ... M_0, via sparse row-scatter per step.
// ---------------------------------------------------------------------------
__global__ void build_P(u16* __restrict__ Pbf) {
    __shared__ float v[2][IMG];
    const int o = blockIdx.x;
    const int t = blockIdx.y;
    const int h = threadIdx.x;

    v[0][h] = (h == o) ? 1.0f : 0.0f;
    int cur = 0;
    __syncthreads();

    for (int i = t - 1; i >= 0; --i) {
        const int nxt = cur ^ 1;
        const float val = v[cur][h];
        v[nxt][h] = 0.0f;
        __syncthreads();
        if (val != 0.0f) {
            const int s = IMG - i;
            // nearest-exact source row: j = clip(floor((h+0.5)*s/256), 0, s-1)
            double xs = (h + 0.5) * (double)s / 256.0;
            int j = (int)xs;
            if (j > s - 1) j = s - 1;
            // bicubic row j of B_i
            double x = (j + 0.5) * 256.0 / (double)s - 0.5;
            int i0 = (int)floor(x);
            double tt = x - (double)i0;
            double w0 = cc2d(tt + 1.0);
            double w1 = cc1d(tt);
            double w2 = cc1d(1.0 - tt);
            double w3 = cc2d(2.0 - tt);
            double w[4] = {w0, w1, w2, w3};
#pragma unroll
            for (int k = 0; k < 4; ++k) {
                int c = i0 - 1 + k;
                c = min(max(c, 0), IMG - 1);
                atomicAdd(&v[nxt][c], val * (float)w[k]);
            }
        }
        __syncthreads();
        cur = nxt;
    }
    Pbf[((size_t)t * IMG + o) * IMG + h] = f2bf(v[cur][h]);
}

// ---------------------------------------------------------------------------
// Kernel 2: X (fp32 [bc][h][w]) -> X^T (bf16 [bc][w][h]), 64x64 LDS tiles.
// ---------------------------------------------------------------------------
__global__ void transpose_cast(const float* __restrict__ X, u16* __restrict__ Xt) {
    __shared__ __align__(16) u16 tile[64][68];  // stride 136B: conflict-light
    const int bc = blockIdx.y;
    const int tx = blockIdx.x & 3, ty = blockIdx.x >> 2;
    const int h0 = ty * 64, w0 = tx * 64;
    const float* Xb = X + (size_t)bc * IMG * IMG;
    u16* Xtb = Xt + (size_t)bc * IMG * IMG;
    const int lid = threadIdx.x;
    const int c4 = (lid & 15) * 4;
    const int r0 = lid >> 4;

#pragma unroll
    for (int it = 0; it < 4; ++it) {
        const int r = r0 + it * 16;
        const float4 vv = *(const float4*)(Xb + (size_t)(h0 + r) * IMG + w0 + c4);
        tile[c4 + 0][r] = f2bf(vv.x);
        tile[c4 + 1][r] = f2bf(vv.y);
        tile[c4 + 2][r] = f2bf(vv.z);
        tile[c4 + 3][r] = f2bf(vv.w);
    }
    __syncthreads();
    const int h4 = (lid & 15) * 4;
    const int wq = lid >> 4;
#pragma unroll
    for (int it = 0; it < 4; ++it) {
        const int w = wq + it * 16;
        ushort4 ov;
        ov.x = tile[w][h4 + 0];
        ov.y = tile[w][h4 + 1];
        ov.z = tile[w][h4 + 2];
        ov.w = tile[w][h4 + 3];
        *(ushort4*)(Xtb + (size_t)(w0 + w) * IMG + h0 + h4) = ov;
    }
}

// ---------------------------------------------------------------------------
// Kernel 3/4: batched GEMM  C[m,n] = sum_k A[m,k] * Bt[n,k]   (256x256x256)
// MODE 0 (gemm1): A = P[t[b]],   Bt = Xt[bc],  C = Y[bc]  (bf16 store)
// MODE 1 (gemm2): A = Y[bc],     Bt = P[t[b]], C = out[bc] (fp32 store)
// 128x128 block tile, 4 waves x (64x64), BK=64, mfma_f32_16x16x32_bf16.
// LDS XOR swizzle on 16B chunks: phys_kb = kb ^ (row & 7)  (write+read).
// ---------------------------------------------------------------------------
template <int MODE>
__global__ __launch_bounds__(256) void gemm_bt(const u16* __restrict__ Pbf,
                                               const u16* __restrict__ Other,
                                               void* __restrict__ Cout,
                                               const int* __restrict__ tarr) {
    __shared__ __align__(16) u16 ldsA[128 * 64];
    __shared__ __align__(16) u16 ldsB[128 * 64];

    const int bc = blockIdx.y;
    const int b = bc / 3;
    const int tsel = tarr[b];

    const u16* A;
    const u16* Bt;
    if (MODE == 0) {
        A = Pbf + (size_t)tsel * IMG * IMG;
        Bt = Other + (size_t)bc * IMG * IMG;
    } else {
        A = Other + (size_t)bc * IMG * IMG;
        Bt = Pbf + (size_t)tsel * IMG * IMG;
    }

    const int tile_m = (blockIdx.x >> 1) * 128;
    const int tile_n = (blockIdx.x & 1) * 128;
    const int tid = threadIdx.x;
    const int lane = tid & 63;
    const int wave = tid >> 6;
    const int wm = (wave >> 1) * 64;
    const int wn = (wave & 1) * 64;

    f32x4 acc[4][4];
#pragma unroll
    for (int i = 0; i < 4; ++i)
#pragma unroll
        for (int j = 0; j < 4; ++j) acc[i][j] = (f32x4){0.f, 0.f, 0.f, 0.f};

    for (int kt = 0; kt < 4; ++kt) {
        __syncthreads();
#pragma unroll
        for (int q = 0; q < 4; ++q) {
            const int id = q * 256 + tid;
            const int row = id >> 3;
            const int kb = id & 7;
            const int kswz = kb ^ (row & 7);
            const uint4 av = *(const uint4*)(A + (size_t)(tile_m + row) * IMG + kt * 64 + kb * 8);
            *(uint4*)(ldsA + row * 64 + kswz * 8) = av;
            const uint4 bv = *(const uint4*)(Bt + (size_t)(tile_n + row) * IMG + kt * 64 + kb * 8);
            *(uint4*)(ldsB + row * 64 + kswz * 8) = bv;
        }
        __syncthreads();
#pragma unroll
        for (int kk = 0; kk < 2; ++kk) {
            const int kb_log = kk * 4 + (lane >> 4);
            bf16x8 afrag[4], bfrag[4];
#pragma unroll
            for (int mi = 0; mi < 4; ++mi) {
                const int r = wm + mi * 16 + (lane & 15);
                afrag[mi] = *(const bf16x8*)(ldsA + r * 64 + ((kb_log ^ (r & 7)) * 8));
            }
#pragma unroll
            for (int nj = 0; nj < 4; ++nj) {
                const int r = wn + nj * 16 + (lane & 15);
                bfrag[nj] = *(const bf16x8*)(ldsB + r * 64 + ((kb_log ^ (r & 7)) * 8));
            }
#pragma unroll
            for (int mi = 0; mi < 4; ++mi)
#pragma unroll
                for (int nj = 0; nj < 4; ++nj)
                    acc[mi][nj] = __builtin_amdgcn_mfma_f32_16x16x32_bf16(
                        afrag[mi], bfrag[nj], acc[mi][nj], 0, 0, 0);
        }
    }

    const int col0 = lane & 15;
    const int row4 = (lane >> 4) * 4;
    if (MODE == 0) {
        u16* C = (u16*)Cout + (size_t)bc * IMG * IMG;
#pragma unroll
        for (int mi = 0; mi < 4; ++mi)
#pragma unroll
            for (int nj = 0; nj < 4; ++nj)
#pragma unroll
                for (int r = 0; r < 4; ++r) {
                    const int ro = tile_m + wm + mi * 16 + row4 + r;
                    const int co = tile_n + wn + nj * 16 + col0;
                    C[(size_t)ro * IMG + co] = f2bf(acc[mi][nj][r]);
                }
    } else {
        float* C = (float*)Cout + (size_t)bc * IMG * IMG;
#pragma unroll
        for (int mi = 0; mi < 4; ++mi)
#pragma unroll
            for (int nj = 0; nj < 4; ++nj)
#pragma unroll
                for (int r = 0; r < 4; ++r) {
                    const int ro = tile_m + wm + mi * 16 + row4 + r;
                    const int co = tile_n + wn + nj * 16 + col0;
                    C[(size_t)ro * IMG + co] = acc[mi][nj][r];
                }
    }
}

// ---------------------------------------------------------------------------
extern "C" void kernel_launch(void* const* d_in, const int* in_sizes, int n_in,
                              void* d_out, int out_size, void* d_ws, size_t ws_size,
                              hipStream_t stream) {
    const float* x0 = (const float*)d_in[0];
    const int* t = (const int*)d_in[1];
    float* out = (float*)d_out;

    // workspace layout: P (20*256*256 bf16 = 2.62MB) | Y (192*256*256 bf16 = 25.2MB)
    u16* Pbf = (u16*)d_ws;
    u16* Y = (u16*)((char*)d_ws + (size_t)TS * IMG * IMG * sizeof(u16));
    // X^T scratch lives in d_out (bf16, 25.2MB of the 50.3MB output buffer);
    // it is fully consumed by gemm1 before gemm2 overwrites d_out.
    u16* Xt = (u16*)d_out;

    hipLaunchKernelGGL(build_P, dim3(IMG, TS), dim3(IMG), 0, stream, Pbf);
    hipLaunchKernelGGL(transpose_cast, dim3(16, 192), dim3(256), 0, stream, x0, Xt);
    hipLaunchKernelGGL((gemm_bt<0>), dim3(4, 192), dim3(256), 0, stream, Pbf, Xt, (void*)Y, t);
    hipLaunchKernelGGL((gemm_bt<1>), dim3(4, 192), dim3(256), 0, stream, Pbf, Y, (void*)out, t);
}